// Round 1
// baseline (205.693 us; speedup 1.0000x reference)
//
#include <hip/hip_runtime.h>

#define T_TOK 8192
#define D_DIM 128
#define N_NEU 4096

// ---------------------------------------------------------------------------
// Kernel A: acts for the LAST 16 tokens only + window means for w=1,2,4,8,16.
// clip(tanh,-5,5) is a no-op since |tanh|<=1.
// 16 blocks x 256 threads, one neuron per thread.
// ---------------------------------------------------------------------------
__global__ void acts_means_kernel(const float* __restrict__ x,   // [T,D]
                                  const float* __restrict__ W,   // [D,N]
                                  const float* __restrict__ b,   // [N]
                                  float* __restrict__ means)     // [6][N] rows 0..4
{
    __shared__ float xs[16][128];
    int tid = threadIdx.x;
    int n = blockIdx.x * 256 + tid;
    for (int idx = tid; idx < 16 * 128; idx += 256) {
        int t = idx >> 7, d = idx & 127;
        xs[t][d] = x[(size_t)(T_TOK - 16 + t) * D_DIM + d];
    }
    __syncthreads();
    float acc[16];
    float bias = b[n];
#pragma unroll
    for (int t = 0; t < 16; ++t) acc[t] = bias;
    for (int d = 0; d < 128; ++d) {
        float w = W[(size_t)d * N_NEU + n];   // coalesced across threads
#pragma unroll
        for (int t = 0; t < 16; ++t) acc[t] += xs[t][d] * w;  // LDS broadcast
    }
#pragma unroll
    for (int t = 0; t < 16; ++t) acc[t] = tanhf(acc[t]);
    // token t local index 15 == last token (global T-1)
    float s1 = acc[15];
    float s2 = s1 + acc[14];
    float s4 = s2 + acc[13] + acc[12];
    float s8 = s4 + acc[11] + acc[10] + acc[9] + acc[8];
    float s16 = s8 + acc[7] + acc[6] + acc[5] + acc[4] + acc[3] + acc[2] + acc[1] + acc[0];
    means[0 * N_NEU + n] = s1;
    means[1 * N_NEU + n] = s2 * 0.5f;
    means[2 * N_NEU + n] = s4 * 0.25f;
    means[3 * N_NEU + n] = s8 * 0.125f;
    means[4 * N_NEU + n] = s16 * 0.0625f;
}

// ---------------------------------------------------------------------------
// Kernel B1: Q/K/V projections of the last 32 tokens. 3 blocks (one per
// matrix) x 512 threads. Thread = (col d, 8-row group).
// ---------------------------------------------------------------------------
__global__ void qkv_kernel(const float* __restrict__ x,
                           const float* __restrict__ Wq, const float* __restrict__ bq,
                           const float* __restrict__ Wk, const float* __restrict__ bk,
                           const float* __restrict__ Wv, const float* __restrict__ bv,
                           float* __restrict__ qkv)   // [3][32][128]
{
    __shared__ float xs[32][128];
    int tid = threadIdx.x;    // 512
    int m = blockIdx.x;       // 0=q,1=k,2=v
    const float* W = (m == 0) ? Wq : ((m == 1) ? Wk : Wv);
    const float* bias = (m == 0) ? bq : ((m == 1) ? bk : bv);
    for (int idx = tid; idx < 32 * 128; idx += 512) {
        int t = idx >> 7, d = idx & 127;
        xs[t][d] = x[(size_t)(T_TOK - 32 + t) * D_DIM + d];
    }
    __syncthreads();
    int d = tid & 127;
    int g = tid >> 7;   // row group: rows g*8 .. g*8+7
    float acc[8];
    float bb = bias[d];
#pragma unroll
    for (int i = 0; i < 8; ++i) acc[i] = bb;
    for (int e = 0; e < 128; ++e) {
        float w = W[e * 128 + d];   // coalesced
#pragma unroll
        for (int i = 0; i < 8; ++i) acc[i] += xs[g * 8 + i][e] * w;
    }
#pragma unroll
    for (int i = 0; i < 8; ++i) qkv[m * 4096 + (g * 8 + i) * 128 + d] = acc[i];
}

// ---------------------------------------------------------------------------
// Kernel B2: 32x32 single-head attention + mean over queries + LayerNorm.
// 1 block x 256 threads. Padded LDS (129/33) to kill bank conflicts.
// ---------------------------------------------------------------------------
__global__ void attn_kernel(const float* __restrict__ qkv,
                            const float* __restrict__ ln_g, const float* __restrict__ ln_b,
                            float* __restrict__ y)   // [128]
{
    __shared__ float qs[32][129], ks[32][129], vs[32][129];
    __shared__ float ps[32][33];
    __shared__ float pbar[32];
    __shared__ float mvec[128];
    __shared__ float stats[2];
    int tid = threadIdx.x;
    for (int idx = tid; idx < 32 * 128; idx += 256) {
        int i = idx >> 7, d = idx & 127;
        qs[i][d] = qkv[idx];
        ks[i][d] = qkv[4096 + idx];
        vs[i][d] = qkv[8192 + idx];
    }
    __syncthreads();
    const float scale = 0.08838834764831845f;  // 1/sqrt(128)
#pragma unroll
    for (int rep = 0; rep < 4; ++rep) {
        int idx = tid + rep * 256;
        int i = idx >> 5, j = idx & 31;
        float acc = 0.f;
        for (int d = 0; d < 128; ++d) acc += qs[i][d] * ks[j][d];
        ps[i][j] = acc * scale;
    }
    __syncthreads();
    if (tid < 32) {        // softmax over row tid
        int i = tid;
        float mx = -1e30f;
        for (int j = 0; j < 32; ++j) mx = fmaxf(mx, ps[i][j]);
        float s = 0.f;
        for (int j = 0; j < 32; ++j) { float e = expf(ps[i][j] - mx); ps[i][j] = e; s += e; }
        float inv = 1.f / s;
        for (int j = 0; j < 32; ++j) ps[i][j] *= inv;
    }
    __syncthreads();
    if (tid < 32) {        // mean over queries of p[:,j]
        int j = tid;
        float s = 0.f;
        for (int i = 0; i < 32; ++i) s += ps[i][j];
        pbar[j] = s * (1.f / 32.f);
    }
    __syncthreads();
    if (tid < 128) {       // attended mean[d] = sum_j pbar[j] * v[j][d]
        int d = tid;
        float s = 0.f;
        for (int j = 0; j < 32; ++j) s += pbar[j] * vs[j][d];
        mvec[d] = s;
    }
    __syncthreads();
    if (tid == 0) {        // layernorm stats (128 elems, trivial)
        float mu = 0.f;
        for (int d = 0; d < 128; ++d) mu += mvec[d];
        mu *= (1.f / 128.f);
        float var = 0.f;
        for (int d = 0; d < 128; ++d) { float t = mvec[d] - mu; var += t * t; }
        var *= (1.f / 128.f);
        stats[0] = mu;
        stats[1] = rsqrtf(var + 1e-5f);
    }
    __syncthreads();
    if (tid < 128) {
        int d = tid;
        y[d] = (mvec[d] - stats[0]) * stats[1] * ln_g[d] + ln_b[d];
    }
}

// ---------------------------------------------------------------------------
// Kernel C: proj = y[1,128] @ projW[128,4096] + projb  -> means row 5
// ---------------------------------------------------------------------------
__global__ void proj_kernel(const float* __restrict__ y, const float* __restrict__ projW,
                            const float* __restrict__ projb, float* __restrict__ means)
{
    __shared__ float ys[128];
    int tid = threadIdx.x;
    int n = blockIdx.x * 256 + tid;
    if (tid < 128) ys[tid] = y[tid];
    __syncthreads();
    float acc = projb[n];
    for (int d = 0; d < 128; ++d) acc += ys[d] * projW[(size_t)d * N_NEU + n];
    means[5 * N_NEU + n] = acc;
}

// ---------------------------------------------------------------------------
// Kernel D: the big GEMV partials.  v[24576] (= means * norm_w, computed on
// the fly) @ comboW[24576][4096].  grid = (4 col-tiles x RB row-chunks),
// 256 threads, 4 cols/thread via float4. Deterministic (no atomics).
// ---------------------------------------------------------------------------
__global__ void combo_partial_kernel(const float* __restrict__ means,  // [6][4096]
                                     const float* __restrict__ ww,     // [6]
                                     const float* __restrict__ comboW, // [24576][4096]
                                     float* __restrict__ part,         // [RB][4096]
                                     int rows_per_chunk)
{
    __shared__ float vsm[512];
    int tid = threadIdx.x;   // 256
    int cb = blockIdx.x;     // 0..3 (col tile of 1024)
    int rb = blockIdx.y;     // row chunk
    float denom = 0.1f;
#pragma unroll
    for (int i = 0; i < 6; ++i) denom += ww[i];
    int row0 = rb * rows_per_chunk;
    for (int r = tid; r < rows_per_chunk; r += 256) {
        int k = row0 + r;
        int seg = k >> 12;           // which window (uniform within chunk)
        int m = k & 4095;
        vsm[r] = means[seg * 4096 + m] * ((ww[seg] + 0.1f) / denom);
    }
    __syncthreads();
    int n4 = cb * 1024 + tid * 4;
    float4 acc = make_float4(0.f, 0.f, 0.f, 0.f);
    const float4* W4 = reinterpret_cast<const float4*>(comboW);
    for (int r = 0; r < rows_per_chunk; ++r) {
        float v = vsm[r];                       // LDS broadcast
        float4 w = W4[((size_t)(row0 + r) * 4096 + n4) >> 2];  // coalesced 16B
        acc.x += v * w.x; acc.y += v * w.y; acc.z += v * w.z; acc.w += v * w.w;
    }
    reinterpret_cast<float4*>(part)[((size_t)rb * 4096 + n4) >> 2] = acc;
}

__global__ void combo_reduce_kernel(const float* __restrict__ part,
                                    const float* __restrict__ bias,
                                    float* __restrict__ out, int nchunks)
{
    int n = blockIdx.x * 256 + threadIdx.x;
    float acc = bias[n];
    for (int c = 0; c < nchunks; ++c) acc += part[(size_t)c * 4096 + n];
    out[n] = acc;
}

// ---------------------------------------------------------------------------
extern "C" void kernel_launch(void* const* d_in, const int* in_sizes, int n_in,
                              void* d_out, int out_size, void* d_ws, size_t ws_size,
                              hipStream_t stream) {
    const float* inputEmbeds = (const float*)d_in[0];
    const float* neuronW     = (const float*)d_in[1];
    const float* neuronB     = (const float*)d_in[2];
    const float* Wq          = (const float*)d_in[3];
    const float* bq          = (const float*)d_in[4];
    const float* Wk          = (const float*)d_in[5];
    const float* bk          = (const float*)d_in[6];
    const float* Wv          = (const float*)d_in[7];
    const float* bv          = (const float*)d_in[8];
    const float* ln_g        = (const float*)d_in[9];
    const float* ln_b        = (const float*)d_in[10];
    const float* projW       = (const float*)d_in[11];
    const float* projb       = (const float*)d_in[12];
    const float* ww          = (const float*)d_in[13];
    const float* comboW      = (const float*)d_in[14];
    const float* combob      = (const float*)d_in[15];
    float* out = (float*)d_out;
    float* ws  = (float*)d_ws;

    float* means = ws;            // 6*4096 = 24576 floats
    float* qkv   = ws + 24576;    // 3*4096 = 12288
    float* y     = ws + 36864;    // 128
    float* part  = ws + 36992;    // RB*4096

    size_t avail = ws_size / 4;
    int RB = 192;                                        // 128 rows/chunk
    if (36992 + (size_t)192 * 4096 > avail) RB = 96;     // 256 rows/chunk
    if (36992 + (size_t)96 * 4096 > avail) RB = 48;      // 512 rows/chunk
    int rpc = 24576 / RB;

    qkv_kernel<<<3, 512, 0, stream>>>(inputEmbeds, Wq, bq, Wk, bk, Wv, bv, qkv);
    attn_kernel<<<1, 256, 0, stream>>>(qkv, ln_g, ln_b, y);
    acts_means_kernel<<<16, 256, 0, stream>>>(inputEmbeds, neuronW, neuronB, means);
    proj_kernel<<<16, 256, 0, stream>>>(y, projW, projb, means);
    combo_partial_kernel<<<dim3(4, RB), 256, 0, stream>>>(means, ww, comboW, part, rpc);
    combo_reduce_kernel<<<16, 256, 0, stream>>>(part, combob, out, RB);
}